// Round 1
// baseline (279.889 us; speedup 1.0000x reference)
//
#include <hip/hip_runtime.h>

// PenalizedMSELoss: out = mean(w * (x - t)^2), w = 3.0 if (4.5 < x < 5.5 && t != 5) else 1.0
// x: float32[N], t: int32[N] (JAX int64 downcast), out: float32[1].
// Memory-bound: 8 B/elem read -> ~268 MB -> ~43 us floor at 6.3 TB/s.

#define LABEL_I   5
#define LOWER_F   4.5f
#define UPPER_F   5.5f
#define PENALTY_F 3.0f

__device__ __forceinline__ float term(float x, int t) {
    float d = x - (float)t;
    float w = (x > LOWER_F && x < UPPER_F && t != LABEL_I) ? PENALTY_F : 1.0f;
    return w * d * d;
}

__global__ __launch_bounds__(256) void penal_mse_kernel(
        const float4* __restrict__ x4,
        const int4*  __restrict__ t4,
        float* __restrict__ out,
        int n4, float inv_n, int n_tail_start, int n_total,
        const float* __restrict__ x_scalar,
        const int*  __restrict__ t_scalar) {
    float sum = 0.0f;

    int idx    = blockIdx.x * blockDim.x + threadIdx.x;
    int stride = gridDim.x * blockDim.x;

    for (int i = idx; i < n4; i += stride) {
        float4 xv = x4[i];
        int4   tv = t4[i];
        sum += term(xv.x, tv.x);
        sum += term(xv.y, tv.y);
        sum += term(xv.z, tv.z);
        sum += term(xv.w, tv.w);
    }

    // Tail (N % 4 != 0) — not taken for N = 33554432, kept for robustness.
    for (int i = n_tail_start + idx; i < n_total; i += stride) {
        sum += term(x_scalar[i], t_scalar[i]);
    }

    // Wave-64 shuffle reduction.
    #pragma unroll
    for (int off = 32; off > 0; off >>= 1)
        sum += __shfl_down(sum, off, 64);

    __shared__ float wsum[4];  // 256 threads / 64 lanes
    int lane = threadIdx.x & 63;
    int wave = threadIdx.x >> 6;
    if (lane == 0) wsum[wave] = sum;
    __syncthreads();

    if (threadIdx.x == 0) {
        float bsum = wsum[0] + wsum[1] + wsum[2] + wsum[3];
        atomicAdd(out, bsum * inv_n);
    }
}

extern "C" void kernel_launch(void* const* d_in, const int* in_sizes, int n_in,
                              void* d_out, int out_size, void* d_ws, size_t ws_size,
                              hipStream_t stream) {
    const float* x = (const float*)d_in[0];
    const int*   t = (const int*)d_in[1];
    float* out = (float*)d_out;

    int n  = in_sizes[0];
    int n4 = n >> 2;           // float4 groups
    int n_tail_start = n4 << 2;
    float inv_n = 1.0f / (float)n;

    // d_out is poisoned to 0xAA before every call — zero it (async, capture-safe).
    hipMemsetAsync(d_out, 0, sizeof(float), stream);

    const int block = 256;
    int grid = 2048;  // 8 blocks/CU on 256 CUs; each thread does ~16 float4 iters
    if (grid > (n4 + block - 1) / block) grid = (n4 + block - 1) / block;
    if (grid < 1) grid = 1;

    penal_mse_kernel<<<grid, block, 0, stream>>>(
        (const float4*)x, (const int4*)t, out,
        n4, inv_n, n_tail_start, n, x, t);
}